// Round 2
// baseline (429.207 us; speedup 1.0000x reference)
//
#include <hip/hip_runtime.h>

#define NN   4096   // nodes
#define DD   512    // in_dim
#define KH   8      // heads
#define RR   64     // sub_dim

// ---------------------------------------------------------------------------
// K0: transpose U [k][d][r] -> Bt [c=k*64+r][d] for the final GEMM
// ---------------------------------------------------------------------------
__global__ __launch_bounds__(256) void transpose_u_kernel(const float* __restrict__ U, float* __restrict__ Bt) {
    int id = blockIdx.x * 256 + threadIdx.x;        // 512*512 = 262144
    int c = id >> 9, d = id & 511;
    int k = c >> 6, r = c & 63;
    Bt[(size_t)c * DD + d] = U[((size_t)k * DD + d) * RR + r];
}

// ---------------------------------------------------------------------------
// K1: Z[k][n][r] = H[n][d] * U[k][d][r], f32.
// grid (32 row-tiles of 128, 8 heads), block 256, each thread 8x4 outputs.
// ---------------------------------------------------------------------------
__global__ __launch_bounds__(256) void zgemm_kernel(const float* __restrict__ H, const float* __restrict__ U,
                                                    float* __restrict__ Zf) {
    __shared__ float As[128][36];   // pad 36: float4-store-aligned (144 B rows)
    __shared__ float Bs[32][64];
    const int t  = threadIdx.x;
    const int i0 = blockIdx.x * 128;
    const int k  = blockIdx.y;
    const int r0 = (t >> 4) * 8;
    const int c0 = (t & 15) * 4;
    float acc[8][4] = {};
    for (int dc = 0; dc < DD; dc += 32) {
        for (int u = t; u < 1024; u += 256) {               // 128x32 f32 = 1024 float4
            int row = u >> 3, q = u & 7;
            *(float4*)&As[row][q * 4] = *(const float4*)(H + (size_t)(i0 + row) * DD + dc + q * 4);
        }
        for (int u = t; u < 512; u += 256) {                // 32x64 f32 = 512 float4
            int ddl = u >> 4, dq = u & 15;
            *(float4*)&Bs[ddl][dq * 4] = *(const float4*)(U + ((size_t)k * DD + dc + ddl) * RR + dq * 4);
        }
        __syncthreads();
        #pragma unroll
        for (int dd = 0; dd < 32; dd += 2) {
            float4 b0 = *(float4*)&Bs[dd][c0];
            float4 b1 = *(float4*)&Bs[dd + 1][c0];
            #pragma unroll
            for (int rr = 0; rr < 8; rr++) {
                float2 a = *(float2*)&As[r0 + rr][dd];
                acc[rr][0] += a.x * b0.x + a.y * b1.x;
                acc[rr][1] += a.x * b0.y + a.y * b1.y;
                acc[rr][2] += a.x * b0.z + a.y * b1.z;
                acc[rr][3] += a.x * b0.w + a.y * b1.w;
            }
        }
        __syncthreads();
    }
    #pragma unroll
    for (int rr = 0; rr < 8; rr++) {
        int row = i0 + r0 + rr;
        float4 o = make_float4(acc[rr][0], acc[rr][1], acc[rr][2], acc[rr][3]);
        *(float4*)(Zf + ((size_t)k * NN + row) * RR + c0) = o;
    }
}

// ---------------------------------------------------------------------------
// K2: sparse masked attention. One block (256 thr) per row i.
// Scan adj row -> neighbor list in LDS; chunked online softmax (flash-style);
// thread owns head t>>5, dims (t&31)*2, accumulates Zagg[i][k*64+r] in regs.
// Bit-equivalent to dense softmax: masked entries (-1e9) underflow to 0.
// ---------------------------------------------------------------------------
__global__ __launch_bounds__(256) void attn_kernel(const float* __restrict__ Zf, const float* __restrict__ adj,
                                                   float* __restrict__ Zagg) {
    const int i = blockIdx.x;
    const int t = threadIdx.x;
    __shared__ int   nbr[NN];          // worst-case neighbor list (16 KB)
    __shared__ int   cnt;
    __shared__ float zi[KH * 72];      // stride 72 floats: 16B-aligned per head
    __shared__ float sc[256 * 9];      // chunk scores / exp, stride 9 breaks conflicts

    if (t == 0) cnt = 0;
    {   // load this row's z_i for all heads
        int k = t >> 5, r = (t & 31) * 2;
        *(float2*)&zi[k * 72 + r] = *(const float2*)(Zf + ((size_t)k * NN + i) * RR + r);
    }
    __syncthreads();

    const float* arow = adj + (size_t)i * NN;
    for (int q = 0; q < 4; q++) {                  // 4096 floats, float4 per thread
        int j = (q * 256 + t) * 4;
        float4 m = *(const float4*)(arow + j);
        if (m.x != 0.f) nbr[atomicAdd(&cnt, 1)] = j;
        if (m.y != 0.f) nbr[atomicAdd(&cnt, 1)] = j + 1;
        if (m.z != 0.f) nbr[atomicAdd(&cnt, 1)] = j + 2;
        if (m.w != 0.f) nbr[atomicAdd(&cnt, 1)] = j + 3;
    }
    __syncthreads();
    const int ntot = cnt;

    const int kown = t >> 5;          // head owned for accumulation (32-lane group)
    const int rown = (t & 31) * 2;    // two dims owned
    const int lane32 = t & 31;
    float2 accv = make_float2(0.f, 0.f);
    float mrun = -3.0e38f, lrun = 0.f;

    for (int base = 0; base < ntot; base += 256) {
        const int c = min(256, ntot - base);
        // scores for chunk: task = (n, head)
        for (int task = t; task < c * 8; task += 256) {
            int n = task >> 3, kk = task & 7;
            int j = nbr[base + n];
            const float4* zp   = (const float4*)(Zf + ((size_t)kk * NN + j) * RR);
            const float4* zik4 = (const float4*)(zi + kk * 72);
            float s = 0.f;
            #pragma unroll
            for (int q = 0; q < 16; q++) {
                float4 v = zp[q];
                float4 a = zik4[q];
                s += a.x * v.x + a.y * v.y + a.z * v.z + a.w * v.w;
            }
            sc[n * 9 + kk] = s * 0.125f;   // 1/sqrt(64)
        }
        __syncthreads();
        // per-head (32-lane group) online-softmax update
        float mx = -3.0e38f;
        for (int n = lane32; n < c; n += 32) mx = fmaxf(mx, sc[n * 9 + kown]);
        #pragma unroll
        for (int off = 16; off; off >>= 1) mx = fmaxf(mx, __shfl_down(mx, off, 32));
        mx = __shfl(mx, 0, 32);
        float mnew = fmaxf(mrun, mx);
        float f = __expf(mrun - mnew);
        accv.x *= f; accv.y *= f; lrun *= f; mrun = mnew;
        float sm = 0.f;
        for (int n = lane32; n < c; n += 32) {
            float e = __expf(sc[n * 9 + kown] - mnew);
            sc[n * 9 + kown] = e;
            sm += e;
        }
        #pragma unroll
        for (int off = 16; off; off >>= 1) sm += __shfl_down(sm, off, 32);
        sm = __shfl(sm, 0, 32);
        lrun += sm;
        __syncthreads();   // exp values visible across waves
        // weighted accumulation of neighbor z vectors
        for (int n = 0; n < c; n++) {
            int j = nbr[base + n];
            float w = sc[n * 9 + kown];                     // LDS broadcast in group
            float2 z2 = *(const float2*)(Zf + ((size_t)kown * NN + j) * RR + rown);
            accv.x += w * z2.x;
            accv.y += w * z2.y;
        }
        __syncthreads();   // before next chunk overwrites sc
    }
    float inv = 1.0f / lrun;   // self-loop guarantees lrun > 0
    *(float2*)(Zagg + (size_t)i * DD + kown * RR + rown) = make_float2(accv.x * inv, accv.y * inv);
}

// ---------------------------------------------------------------------------
// K3: out = relu(H + 0.5 * Zagg x Bt - thr). Same tiling as K1.
// ---------------------------------------------------------------------------
__global__ __launch_bounds__(256) void outgemm_kernel(const float* __restrict__ Zagg, const float* __restrict__ Bt,
                                                      const float* __restrict__ H, const float* __restrict__ thr,
                                                      float* __restrict__ out) {
    __shared__ float As[128][36];
    __shared__ float Bs[32][64];
    const int t  = threadIdx.x;
    const int i0 = blockIdx.x * 128;
    const int d0 = blockIdx.y * 64;
    const int r0 = (t >> 4) * 8;
    const int c0 = (t & 15) * 4;
    float acc[8][4] = {};
    for (int cc = 0; cc < DD; cc += 32) {
        for (int u = t; u < 1024; u += 256) {               // 128x32 f32 = 1024 float4
            int row = u >> 3, q = u & 7;
            *(float4*)&As[row][q * 4] = *(const float4*)(Zagg + (size_t)(i0 + row) * DD + cc + q * 4);
        }
        for (int u = t; u < 512; u += 256) {                // 32x64 f32 = 512 float4
            int ccl = u >> 4, dq = u & 15;
            *(float4*)&Bs[ccl][dq * 4] = *(const float4*)(Bt + (size_t)(cc + ccl) * DD + d0 + dq * 4);
        }
        __syncthreads();
        #pragma unroll
        for (int dd = 0; dd < 32; dd += 2) {
            float4 b0 = *(float4*)&Bs[dd][c0];
            float4 b1 = *(float4*)&Bs[dd + 1][c0];
            #pragma unroll
            for (int rr = 0; rr < 8; rr++) {
                float2 a = *(float2*)&As[r0 + rr][dd];
                acc[rr][0] += a.x * b0.x + a.y * b1.x;
                acc[rr][1] += a.x * b0.y + a.y * b1.y;
                acc[rr][2] += a.x * b0.z + a.y * b1.z;
                acc[rr][3] += a.x * b0.w + a.y * b1.w;
            }
        }
        __syncthreads();
    }
    float4 th = *(const float4*)(thr + d0 + c0);
    #pragma unroll
    for (int rr = 0; rr < 8; rr++) {
        int row = i0 + r0 + rr;
        float4 h = *(const float4*)(H + (size_t)row * DD + d0 + c0);
        float4 o;
        o.x = fmaxf(h.x + 0.5f * acc[rr][0] - th.x, 0.f);
        o.y = fmaxf(h.y + 0.5f * acc[rr][1] - th.y, 0.f);
        o.z = fmaxf(h.z + 0.5f * acc[rr][2] - th.z, 0.f);
        o.w = fmaxf(h.w + 0.5f * acc[rr][3] - th.w, 0.f);
        *(float4*)(out + (size_t)row * DD + d0 + c0) = o;
    }
}

// ---------------------------------------------------------------------------
// K4: orthogonality loss = sum_{k<l} ||U_k^T U_l||_F^2.
// grid = 28 pairs * 16 s-tiles; thread computes gram[r][s] (512-dot), square,
// block-reduce, atomicAdd into f32 accumulator in ws.
// ---------------------------------------------------------------------------
__global__ __launch_bounds__(256) void orth_kernel(const float* __restrict__ U, float* __restrict__ loss) {
    int pb = blockIdx.x >> 4;
    int stile = blockIdx.x & 15;
    int idx = pb, k = 0, l = 1;
    for (int kk = 0; kk < 8; kk++) {
        int c = 7 - kk;
        if (idx < c) { k = kk; l = kk + 1 + idx; break; }
        idx -= c;
    }
    int t = threadIdx.x;
    int r = t & 63;
    int s = stile * 4 + (t >> 6);
    const float* Uk = U + (size_t)k * DD * RR;
    const float* Ul = U + (size_t)l * DD * RR;
    float acc = 0.f;
    for (int d = 0; d < DD; d++) {
        acc += Uk[d * RR + r] * Ul[d * RR + s];   // Uk coalesced, Ul wave-uniform
    }
    float v = acc * acc;
    #pragma unroll
    for (int off = 32; off; off >>= 1) v += __shfl_down(v, off, 64);
    __shared__ float red[4];
    if ((t & 63) == 0) red[t >> 6] = v;
    __syncthreads();
    if (t == 0) atomicAdd(loss, red[0] + red[1] + red[2] + red[3]);
}

__global__ void loss_fin_kernel(const float* __restrict__ lossf, float* __restrict__ out) {
    out[0] = lossf[0];
}

// ---------------------------------------------------------------------------
extern "C" void kernel_launch(void* const* d_in, const int* in_sizes, int n_in,
                              void* d_out, int out_size, void* d_ws, size_t ws_size,
                              hipStream_t stream) {
    const float* H   = (const float*)d_in[0];
    const float* adj = (const float*)d_in[1];
    const float* U   = (const float*)d_in[2];
    const float* thr = (const float*)d_in[3];
    float* out = (float*)d_out;

    char* ws = (char*)d_ws;
    float* lossA = (float*)ws;                                    // 4 B
    float* Zf    = (float*)(ws + 1024);                           // 8*4096*64 f32 = 8 MB
    float* Zagg  = (float*)(ws + 1024 + 8u * 1024 * 1024);        // 4096*512 f32 = 8 MB
    float* Bt    = (float*)(ws + 1024 + 16u * 1024 * 1024);       // 512*512 f32 = 1 MB

    hipMemsetAsync(lossA, 0, sizeof(float), stream);
    transpose_u_kernel<<<512 * 512 / 256, 256, 0, stream>>>(U, Bt);
    zgemm_kernel<<<dim3(NN / 128, KH), 256, 0, stream>>>(H, U, Zf);
    attn_kernel<<<NN, 256, 0, stream>>>(Zf, adj, Zagg);
    outgemm_kernel<<<dim3(NN / 128, DD / 64), 256, 0, stream>>>(Zagg, Bt, H, thr, out);
    orth_kernel<<<28 * 16, 256, 0, stream>>>(U, lossA);
    loss_fin_kernel<<<1, 1, 0, stream>>>(lossA, out + (size_t)NN * DD);
}

// Round 3
// 199.399 us; speedup vs baseline: 2.1525x; 2.1525x over previous
//
#include <hip/hip_runtime.h>
#include <hip/hip_bf16.h>

#define NN   4096   // nodes
#define DD   512    // in_dim (= 8 heads * 64)
#define KH   8      // heads
#define RR   64     // sub_dim
#define CAP  256    // max neighbors per row (deg ~ Binomial(4096,0.01)+1 ~ 42±6.4; 256 is >30 sigma)

typedef unsigned short u16;
typedef unsigned int   u32;
typedef __attribute__((ext_vector_type(8))) short short8;  // 8 bf16 = 4 VGPRs (MFMA A/B frag)
typedef __attribute__((ext_vector_type(4))) float f32x4;   // MFMA C/D frag

__device__ __forceinline__ float bflo(u32 v){ union{u32 i; float f;} c; c.i = v << 16;        return c.f; }
__device__ __forceinline__ float bfhi(u32 v){ union{u32 i; float f;} c; c.i = v & 0xFFFF0000u; return c.f; }
__device__ __forceinline__ float bf1(u16 v){ union{u32 i; float f;} c; c.i = ((u32)v) << 16;  return c.f; }
__device__ __forceinline__ u16 f2bf(float f){ __hip_bfloat16 h = __float2bfloat16(f); return *reinterpret_cast<u16*>(&h); }

// ---------------------------------------------------------------------------
// P0: H (f32) -> Hb (bf16). 512K float4 groups.
// ---------------------------------------------------------------------------
__global__ __launch_bounds__(256) void prep_h(const float* __restrict__ H, u16* __restrict__ Hb) {
    size_t id = (size_t)blockIdx.x * 256 + threadIdx.x;
    float4 v = *(const float4*)(H + id * 4);
    ushort4 o; o.x = f2bf(v.x); o.y = f2bf(v.y); o.z = f2bf(v.z); o.w = f2bf(v.w);
    *(ushort4*)(Hb + id * 4) = o;
}

// ---------------------------------------------------------------------------
// P1: build both B^T operands in bf16 from U [k][d][r] (f32):
//   Bt1[c=k*64+r][d]  (zgemm B^T: N=c, K=d)
//   Bt2[d][c=k*64+r]  (outgemm B^T: N=d, K=c)
// One block per (k, 64-d tile); coalesced f32 read -> LDS -> coalesced bf16 writes.
// ---------------------------------------------------------------------------
__global__ __launch_bounds__(256) void prep_u(const float* __restrict__ U, u16* __restrict__ Bt1, u16* __restrict__ Bt2) {
    __shared__ float tile[64][65];   // [dd][r], pad 65 breaks pow2 stride
    int b = blockIdx.x, t = threadIdx.x;
    int k = b >> 3, d0 = (b & 7) * 64;
    #pragma unroll
    for (int s = 0; s < 4; s++) {
        int u = t + 256 * s;               // 0..1023
        int dd = u >> 4, rq = u & 15;
        float4 v = *(const float4*)(U + ((size_t)(k * DD + d0 + dd)) * RR + rq * 4);
        tile[dd][rq * 4 + 0] = v.x; tile[dd][rq * 4 + 1] = v.y;
        tile[dd][rq * 4 + 2] = v.z; tile[dd][rq * 4 + 3] = v.w;
    }
    __syncthreads();
    {   // Bt1[k*64+r][d0+dd]
        int r = t >> 2;
        #pragma unroll
        for (int ii = 0; ii < 16; ii++) {
            int dd = (t & 3) * 16 + ii;
            Bt1[(size_t)(k * RR + r) * DD + d0 + dd] = f2bf(tile[dd][r]);
        }
    }
    {   // Bt2[d0+dd][k*64+r]
        int dd = t >> 2, rb = (t & 3) * 16;
        #pragma unroll
        for (int ii = 0; ii < 16; ii++) {
            Bt2[(size_t)(d0 + dd) * DD + k * RR + rb + ii] = f2bf(tile[dd][rb + ii]);
        }
    }
}

// ---------------------------------------------------------------------------
// P2: neighbor extraction. One block per row: coalesced mask scan -> compacted
// index list (order irrelevant; softmax sum order differs anyway).
// ---------------------------------------------------------------------------
__global__ __launch_bounds__(256) void pass1_nbr(const float* __restrict__ adj, int* __restrict__ nlist,
                                                 int* __restrict__ cnt) {
    int i = blockIdx.x, t = threadIdx.x;
    __shared__ int cntS;
    __shared__ int list[CAP];
    if (t == 0) cntS = 0;
    __syncthreads();
    const float* arow = adj + (size_t)i * NN;
    #pragma unroll
    for (int q = 0; q < 4; q++) {
        int j = (q * 256 + t) * 4;
        float4 m = *(const float4*)(arow + j);
        if (m.x != 0.f) { int p = atomicAdd(&cntS, 1); if (p < CAP) list[p] = j;     }
        if (m.y != 0.f) { int p = atomicAdd(&cntS, 1); if (p < CAP) list[p] = j + 1; }
        if (m.z != 0.f) { int p = atomicAdd(&cntS, 1); if (p < CAP) list[p] = j + 2; }
        if (m.w != 0.f) { int p = atomicAdd(&cntS, 1); if (p < CAP) list[p] = j + 3; }
    }
    __syncthreads();
    int n = min(cntS, CAP);
    for (int u = t; u < n; u += 256) nlist[(size_t)i * CAP + u] = list[u];
    if (t == 0) cnt[i] = n;
}

// ---------------------------------------------------------------------------
// K1: Zb[n][c=k*64+r] = Hb[n][:] . Bt1[c][:]   (M=4096, N=512, K=512, bf16 MFMA)
// 128x64 tile, 256 blocks, 4 waves each computing 64x32 (4x2 16x16x32 frags).
// LDS row stride 40 shorts (80 B): frag ds_read_b128 lands 2-way conflicts (free).
// ---------------------------------------------------------------------------
__global__ __launch_bounds__(256) void zgemm_mfma(const u16* __restrict__ Hb, const u16* __restrict__ Bt1,
                                                  u16* __restrict__ Zb) {
    __shared__ short As[128][40];
    __shared__ short Bs[64][40];
    const int t = threadIdx.x;
    const int i0 = blockIdx.x * 128, n0 = blockIdx.y * 64;
    const int w = t >> 6, lane = t & 63;
    const int lm = lane & 15, lg = lane >> 4;
    const int mo = (w >> 1) * 64, no = (w & 1) * 32;
    f32x4 acc[4][2] = {};
    for (int kc = 0; kc < DD; kc += 32) {
        #pragma unroll
        for (int s = 0; s < 2; s++) {                       // A: 512 16B-chunks
            int c = t + 256 * s; int row = c >> 2, g = c & 3;
            short8 v = *(const short8*)(Hb + (size_t)(i0 + row) * DD + kc + g * 8);
            *(short8*)&As[row][g * 8] = v;
        }
        {   int n = t >> 2, g = t & 3;                      // B: 256 16B-chunks
            short8 v = *(const short8*)(Bt1 + (size_t)(n0 + n) * DD + kc + g * 8);
            *(short8*)&Bs[n][g * 8] = v;
        }
        __syncthreads();
        short8 af[4], bfr[2];
        #pragma unroll
        for (int a = 0; a < 4; a++) af[a] = *(const short8*)&As[mo + a * 16 + lm][lg * 8];
        #pragma unroll
        for (int b = 0; b < 2; b++) bfr[b] = *(const short8*)&Bs[no + b * 16 + lm][lg * 8];
        #pragma unroll
        for (int a = 0; a < 4; a++)
            #pragma unroll
            for (int b = 0; b < 2; b++)
                acc[a][b] = __builtin_amdgcn_mfma_f32_16x16x32_bf16(af[a], bfr[b], acc[a][b], 0, 0, 0);
        __syncthreads();
    }
    // C/D layout: col = lane&15, row = (lane>>4)*4 + reg  [m89-verified]
    #pragma unroll
    for (int a = 0; a < 4; a++)
        #pragma unroll
        for (int b = 0; b < 2; b++)
            #pragma unroll
            for (int q = 0; q < 4; q++) {
                int row = i0 + mo + a * 16 + lg * 4 + q;
                int col = n0 + no + b * 16 + lm;
                Zb[(size_t)row * DD + col] = f2bf(acc[a][b][q]);
            }
}

// ---------------------------------------------------------------------------
// K2: attention. One block per row, wave w handles heads {w, w+4}.
// Chunk 64 neighbors: lane c gathers z_j (128 B contiguous bf16), dots vs zi
// (LDS broadcast), stages z into LDS; wave-shuffle online softmax; lane r
// aggregates dim r from LDS. Bit-equiv to dense masked softmax.
// ---------------------------------------------------------------------------
__global__ __launch_bounds__(256) void attn2(const u16* __restrict__ Zb, const int* __restrict__ nlist,
                                             const int* __restrict__ cnt, u16* __restrict__ Zaggb) {
    const int i = blockIdx.x, t = threadIdx.x;
    const int w = t >> 6, lane = t & 63;
    __shared__ int   nbrS[CAP];
    __shared__ float ziS[DD];
    __shared__ short zbuf[4][64][72];   // [wave][nbr][r], stride 72 (144 B, 16B-aligned)
    __shared__ float wS[4][64];
    const int ci = cnt[i];
    for (int u = t; u < ci; u += 256) nbrS[u] = nlist[(size_t)i * CAP + u];
    {   u32 v = *(const u32*)(Zb + (size_t)i * DD + t * 2);
        ziS[t * 2] = bflo(v); ziS[t * 2 + 1] = bfhi(v);
    }
    __syncthreads();
    const int nchunk = (ci + 63) >> 6;
    for (int hh = 0; hh < 2; hh++) {
        const int k = w + hh * 4;
        const float* zik = ziS + k * 64;
        float m = -3.0e38f, l = 0.f, acc = 0.f;
        for (int ch = 0; ch < nchunk; ch++) {
            const int base = ch * 64;
            const int cact = min(64, ci - base);
            const int j = nbrS[base + ((lane < cact) ? lane : 0)];
            const uint4* zp = (const uint4*)(Zb + (size_t)j * DD + k * 64);
            float s = 0.f;
            #pragma unroll
            for (int q = 0; q < 8; q++) {
                uint4 v = zp[q];
                const float* zq = zik + q * 8;
                s += bflo(v.x) * zq[0] + bfhi(v.x) * zq[1]
                   + bflo(v.y) * zq[2] + bfhi(v.y) * zq[3]
                   + bflo(v.z) * zq[4] + bfhi(v.z) * zq[5]
                   + bflo(v.w) * zq[6] + bfhi(v.w) * zq[7];
                *(uint4*)&zbuf[w][lane][q * 8] = v;
            }
            s *= 0.125f;                       // 1/sqrt(64)
            if (lane >= cact) s = -3.0e38f;
            float mx = s;
            #pragma unroll
            for (int off = 32; off; off >>= 1) mx = fmaxf(mx, __shfl_xor(mx, off));
            const float mnew = fmaxf(m, mx);
            const float scale = __expf(m - mnew);
            const float e = (lane < cact) ? __expf(s - mnew) : 0.f;
            float se = e;
            #pragma unroll
            for (int off = 32; off; off >>= 1) se += __shfl_xor(se, off);
            l = l * scale + se;
            m = mnew;
            acc *= scale;
            wS[w][lane] = e;
            __syncthreads();                   // all waves iterate uniformly (same ci)
            for (int c = 0; c < cact; c++)
                acc += wS[w][c] * bf1(zbuf[w][c][lane]);   // w broadcast; z 2-way (free)
            __syncthreads();
        }
        Zaggb[(size_t)i * DD + k * 64 + lane] = f2bf(acc / l);   // self-loop => l > 0
    }
}

// ---------------------------------------------------------------------------
// K3: out = relu(H + 0.5 * (Zaggb . Bt2^T) - thr), f32 out. Same MFMA tiling.
// ---------------------------------------------------------------------------
__global__ __launch_bounds__(256) void outgemm_mfma(const u16* __restrict__ Ab, const u16* __restrict__ Btb,
                                                    const float* __restrict__ H, const float* __restrict__ thr,
                                                    float* __restrict__ out) {
    __shared__ short As[128][40];
    __shared__ short Bs[64][40];
    const int t = threadIdx.x;
    const int i0 = blockIdx.x * 128, n0 = blockIdx.y * 64;
    const int w = t >> 6, lane = t & 63;
    const int lm = lane & 15, lg = lane >> 4;
    const int mo = (w >> 1) * 64, no = (w & 1) * 32;
    f32x4 acc[4][2] = {};
    for (int kc = 0; kc < DD; kc += 32) {
        #pragma unroll
        for (int s = 0; s < 2; s++) {
            int c = t + 256 * s; int row = c >> 2, g = c & 3;
            short8 v = *(const short8*)(Ab + (size_t)(i0 + row) * DD + kc + g * 8);
            *(short8*)&As[row][g * 8] = v;
        }
        {   int n = t >> 2, g = t & 3;
            short8 v = *(const short8*)(Btb + (size_t)(n0 + n) * DD + kc + g * 8);
            *(short8*)&Bs[n][g * 8] = v;
        }
        __syncthreads();
        short8 af[4], bfr[2];
        #pragma unroll
        for (int a = 0; a < 4; a++) af[a] = *(const short8*)&As[mo + a * 16 + lm][lg * 8];
        #pragma unroll
        for (int b = 0; b < 2; b++) bfr[b] = *(const short8*)&Bs[no + b * 16 + lm][lg * 8];
        #pragma unroll
        for (int a = 0; a < 4; a++)
            #pragma unroll
            for (int b = 0; b < 2; b++)
                acc[a][b] = __builtin_amdgcn_mfma_f32_16x16x32_bf16(af[a], bfr[b], acc[a][b], 0, 0, 0);
        __syncthreads();
    }
    #pragma unroll
    for (int b = 0; b < 2; b++) {
        const int col = n0 + no + b * 16 + lm;
        const float th = thr[col];
        #pragma unroll
        for (int a = 0; a < 4; a++)
            #pragma unroll
            for (int q = 0; q < 4; q++) {
                int row = i0 + mo + a * 16 + lg * 4 + q;
                float h = H[(size_t)row * DD + col];
                out[(size_t)row * DD + col] = fmaxf(h + 0.5f * acc[a][b][q] - th, 0.f);
            }
    }
}

// ---------------------------------------------------------------------------
// K4: orthogonality loss (unchanged; tiny).
// ---------------------------------------------------------------------------
__global__ __launch_bounds__(256) void orth_kernel(const float* __restrict__ U, float* __restrict__ loss) {
    int pb = blockIdx.x >> 4;
    int stile = blockIdx.x & 15;
    int idx = pb, k = 0, l = 1;
    for (int kk = 0; kk < 8; kk++) {
        int c = 7 - kk;
        if (idx < c) { k = kk; l = kk + 1 + idx; break; }
        idx -= c;
    }
    int t = threadIdx.x;
    int r = t & 63;
    int s = stile * 4 + (t >> 6);
    const float* Uk = U + (size_t)k * DD * RR;
    const float* Ul = U + (size_t)l * DD * RR;
    float acc = 0.f;
    for (int d = 0; d < DD; d++) {
        acc += Uk[d * RR + r] * Ul[d * RR + s];
    }
    float v = acc * acc;
    #pragma unroll
    for (int off = 32; off; off >>= 1) v += __shfl_down(v, off, 64);
    __shared__ float red[4];
    if ((t & 63) == 0) red[t >> 6] = v;
    __syncthreads();
    if (t == 0) atomicAdd(loss, red[0] + red[1] + red[2] + red[3]);
}

__global__ void loss_fin_kernel(const float* __restrict__ lossf, float* __restrict__ out) {
    out[0] = lossf[0];
}

// ---------------------------------------------------------------------------
extern "C" void kernel_launch(void* const* d_in, const int* in_sizes, int n_in,
                              void* d_out, int out_size, void* d_ws, size_t ws_size,
                              hipStream_t stream) {
    const float* H   = (const float*)d_in[0];
    const float* adj = (const float*)d_in[1];
    const float* U   = (const float*)d_in[2];
    const float* thr = (const float*)d_in[3];
    float* out = (float*)d_out;

    char* ws = (char*)d_ws;
    float* lossA = (float*)ws;                                         // 4 B
    u16*   Hb    = (u16*)(ws + 1024);                                  // 4 MB
    u16*   Zb    = (u16*)(ws + 1024 + 4u  * 1024 * 1024);              // 4 MB
    u16*   Zaggb = (u16*)(ws + 1024 + 8u  * 1024 * 1024);              // 4 MB
    u16*   Bt1   = (u16*)(ws + 1024 + 12u * 1024 * 1024);              // 512 KB
    u16*   Bt2   = (u16*)(ws + 1024 + 12u * 1024 * 1024 + 512u * 1024);// 512 KB
    int*   nlist = (int*)(ws + 1024 + 13u * 1024 * 1024);              // 4 MB
    int*   cnt   = (int*)(ws + 1024 + 17u * 1024 * 1024);              // 16 KB

    hipMemsetAsync(lossA, 0, sizeof(float), stream);
    prep_h<<<2048, 256, 0, stream>>>(H, Hb);
    prep_u<<<64, 256, 0, stream>>>(U, Bt1, Bt2);
    pass1_nbr<<<NN, 256, 0, stream>>>(adj, nlist, cnt);
    zgemm_mfma<<<dim3(32, 8), 256, 0, stream>>>(Hb, Bt1, Zb);
    attn2<<<NN, 256, 0, stream>>>(Zb, nlist, cnt, Zaggb);
    outgemm_mfma<<<dim3(32, 8), 256, 0, stream>>>(Zaggb, Bt2, H, thr, out);
    orth_kernel<<<28 * 16, 256, 0, stream>>>(U, lossA);
    loss_fin_kernel<<<1, 1, 0, stream>>>(lossA, out + (size_t)NN * DD);
}

// Round 4
// 180.401 us; speedup vs baseline: 2.3792x; 1.1053x over previous
//
#include <hip/hip_runtime.h>
#include <hip/hip_bf16.h>

#define NN   4096   // nodes
#define DD   512    // in_dim (= 8 heads * 64)
#define KH   8      // heads
#define RR   64     // sub_dim
#define CAP  256    // max neighbors kept (deg ~ 42 +- 6.4; 256 is >30 sigma)

typedef unsigned short u16;
typedef unsigned int   u32;
typedef __attribute__((ext_vector_type(8))) short short8;  // 8 bf16 (MFMA A/B frag)
typedef __attribute__((ext_vector_type(4))) float f32x4;   // MFMA C/D frag

__device__ __forceinline__ float bflo(u32 v){ union{u32 i; float f;} c; c.i = v << 16;        return c.f; }
__device__ __forceinline__ float bfhi(u32 v){ union{u32 i; float f;} c; c.i = v & 0xFFFF0000u; return c.f; }
__device__ __forceinline__ float bf1(u16 v){ union{u32 i; float f;} c; c.i = ((u32)v) << 16;  return c.f; }
__device__ __forceinline__ u16 f2bf(float f){ __hip_bfloat16 h = __float2bfloat16(f); return *reinterpret_cast<u16*>(&h); }

// ---------------------------------------------------------------------------
// P0 (merged prep): b<2048: H->Hb bf16 cast. b<2112: U -> Bt1/Bt2 bf16
// transposes. b==2112: zero the loss accumulator (replaces memset dispatch).
// ---------------------------------------------------------------------------
__global__ __launch_bounds__(256) void prep_all(const float* __restrict__ H, const float* __restrict__ U,
                                                u16* __restrict__ Hb, u16* __restrict__ Bt1,
                                                u16* __restrict__ Bt2, float* __restrict__ lossA) {
    __shared__ float tile[64][65];
    int b = blockIdx.x, t = threadIdx.x;
    if (b < 2048) {
        size_t id = (size_t)b * 256 + t;
        float4 v = *(const float4*)(H + id * 4);
        ushort4 o; o.x = f2bf(v.x); o.y = f2bf(v.y); o.z = f2bf(v.z); o.w = f2bf(v.w);
        *(ushort4*)(Hb + id * 4) = o;
        return;
    }
    if (b == 2112) { if (t == 0) lossA[0] = 0.f; return; }
    int b2 = b - 2048;
    int k = b2 >> 3, d0 = (b2 & 7) * 64;
    #pragma unroll
    for (int s = 0; s < 4; s++) {
        int u = t + 256 * s;               // 0..1023
        int dd = u >> 4, rq = u & 15;
        float4 v = *(const float4*)(U + ((size_t)(k * DD + d0 + dd)) * RR + rq * 4);
        tile[dd][rq * 4 + 0] = v.x; tile[dd][rq * 4 + 1] = v.y;
        tile[dd][rq * 4 + 2] = v.z; tile[dd][rq * 4 + 3] = v.w;
    }
    __syncthreads();
    {   // Bt1[k*64+r][d0+dd]
        int r = t >> 2;
        #pragma unroll
        for (int ii = 0; ii < 16; ii++) {
            int dd = (t & 3) * 16 + ii;
            Bt1[(size_t)(k * RR + r) * DD + d0 + dd] = f2bf(tile[dd][r]);
        }
    }
    {   // Bt2[d0+dd][k*64+r]
        int dd = t >> 2, rb = (t & 3) * 16;
        #pragma unroll
        for (int ii = 0; ii < 16; ii++) {
            Bt2[(size_t)(d0 + dd) * DD + k * RR + rb + ii] = f2bf(tile[dd][rb + ii]);
        }
    }
}

// ---------------------------------------------------------------------------
// K1: Zb[n][c=k*64+r] = Hb[n][:] . Bt1[c][:]   (M=4096, N=512, K=512, bf16 MFMA)
// 64x64 tile, 512 blocks (2/CU), wave w computes rows [w*16,w*16+16) x 64 cols.
// ---------------------------------------------------------------------------
__global__ __launch_bounds__(256) void zgemm_mfma(const u16* __restrict__ Hb, const u16* __restrict__ Bt1,
                                                  u16* __restrict__ Zb) {
    __shared__ short As[64][40];   // stride 40 shorts: b128 frag reads 2-way (free)
    __shared__ short Bs[64][40];
    const int t = threadIdx.x;
    const int i0 = blockIdx.x * 64, n0 = blockIdx.y * 64;
    const int w = t >> 6, lane = t & 63;
    const int lm = lane & 15, lg = lane >> 4;
    f32x4 acc[4] = {};
    for (int kc = 0; kc < DD; kc += 32) {
        {   int row = t >> 2, g = t & 3;
            *(short8*)&As[row][g * 8] = *(const short8*)(Hb  + (size_t)(i0 + row) * DD + kc + g * 8);
            *(short8*)&Bs[row][g * 8] = *(const short8*)(Bt1 + (size_t)(n0 + row) * DD + kc + g * 8);
        }
        __syncthreads();
        short8 af = *(const short8*)&As[w * 16 + lm][lg * 8];
        #pragma unroll
        for (int b = 0; b < 4; b++) {
            short8 bfr = *(const short8*)&Bs[b * 16 + lm][lg * 8];
            acc[b] = __builtin_amdgcn_mfma_f32_16x16x32_bf16(af, bfr, acc[b], 0, 0, 0);
        }
        __syncthreads();
    }
    // C/D: col = lane&15, row = (lane>>4)*4 + reg  [m89-verified]
    #pragma unroll
    for (int b = 0; b < 4; b++)
        #pragma unroll
        for (int q = 0; q < 4; q++) {
            int row = i0 + w * 16 + lg * 4 + q;
            int col = n0 + b * 16 + lm;
            Zb[(size_t)row * DD + col] = f2bf(acc[b][q]);
        }
}

// ---------------------------------------------------------------------------
// K2: fused mask-scan + sparse attention. One block (512 thr) per row i,
// wave k = head k. Chunk-16 neighbor staging; quad gather (4 lanes x 32 B per
// neighbor); shuffle softmax; zero cross-wave barriers after setup (zbuf/wS
// are per-wave, wave64 is lockstep). Bit-equiv to dense masked softmax
// (-1e9 masked scores underflow to exp=0 in f32).
// ---------------------------------------------------------------------------
__global__ __launch_bounds__(512) void attn3(const u16* __restrict__ Zb, const float* __restrict__ adj,
                                             u16* __restrict__ Zaggb) {
    const int i = blockIdx.x, t = threadIdx.x;
    const int k = t >> 6, lane = t & 63;
    __shared__ int   nbrS[CAP];
    __shared__ int   cntS;
    __shared__ float ziS[DD];
    __shared__ short zbuf[KH][16][72];   // per-wave chunk staging (144 B rows)
    __shared__ float wS[KH][16];
    if (t == 0) cntS = 0;
    __syncthreads();
    const float* arow = adj + (size_t)i * NN;
    #pragma unroll
    for (int qq = 0; qq < 2; qq++) {     // 4096 floats, float4 per thread x2
        int j = (qq * 512 + t) * 4;
        float4 mv = *(const float4*)(arow + j);
        if (mv.x != 0.f) { int p = atomicAdd(&cntS, 1); if (p < CAP) nbrS[p] = j;     }
        if (mv.y != 0.f) { int p = atomicAdd(&cntS, 1); if (p < CAP) nbrS[p] = j + 1; }
        if (mv.z != 0.f) { int p = atomicAdd(&cntS, 1); if (p < CAP) nbrS[p] = j + 2; }
        if (mv.w != 0.f) { int p = atomicAdd(&cntS, 1); if (p < CAP) nbrS[p] = j + 3; }
    }
    if (t < 256) {
        u32 v = *(const u32*)(Zb + (size_t)i * DD + t * 2);
        ziS[t * 2] = bflo(v); ziS[t * 2 + 1] = bfhi(v);
    }
    __syncthreads();
    const int ci = min(cntS, CAP);       // >=1 (self-loop)

    const int q = lane & 3, nl = lane >> 2;           // quad structure
    const float* zik = ziS + k * 64 + q * 16;
    float m = -3.0e38f, l = 0.f, acc = 0.f;
    const int nchunk = (ci + 15) >> 4;
    for (int ch = 0; ch < nchunk; ch++) {
        const int base = ch * 16;
        const int cact = min(16, ci - base);
        const int j = nbrS[base + ((nl < cact) ? nl : 0)];
        const uint4* zp = (const uint4*)(Zb + (size_t)j * DD + k * 64 + q * 16);
        uint4 v0 = zp[0], v1 = zp[1];
        float s = bflo(v0.x) * zik[0]  + bfhi(v0.x) * zik[1]
                + bflo(v0.y) * zik[2]  + bfhi(v0.y) * zik[3]
                + bflo(v0.z) * zik[4]  + bfhi(v0.z) * zik[5]
                + bflo(v0.w) * zik[6]  + bfhi(v0.w) * zik[7]
                + bflo(v1.x) * zik[8]  + bfhi(v1.x) * zik[9]
                + bflo(v1.y) * zik[10] + bfhi(v1.y) * zik[11]
                + bflo(v1.z) * zik[12] + bfhi(v1.z) * zik[13]
                + bflo(v1.w) * zik[14] + bfhi(v1.w) * zik[15];
        *(uint4*)&zbuf[k][nl][q * 16]     = v0;       // stage for aggregation
        *(uint4*)&zbuf[k][nl][q * 16 + 8] = v1;
        s += __shfl_xor(s, 1); s += __shfl_xor(s, 2); // full dot, quad-replicated
        s *= 0.125f;                                  // 1/sqrt(64)
        if (nl >= cact) s = -3.0e38f;
        float mx = s;
        #pragma unroll
        for (int off = 4; off < 64; off <<= 1) mx = fmaxf(mx, __shfl_xor(mx, off));
        const float mnew = fmaxf(m, mx);
        const float scale = __expf(m - mnew);
        const float e = (nl < cact) ? __expf(s - mnew) : 0.f;
        float se = e;
        #pragma unroll
        for (int off = 4; off < 64; off <<= 1) se += __shfl_xor(se, off);  // sums 16 quads once each
        l = l * scale + se;
        m = mnew;
        acc *= scale;
        if (q == 0) wS[k][nl] = e;
        // aggregation: lane = dim r; per-wave LDS, wave-synchronous (no barrier)
        for (int c = 0; c < cact; c++)
            acc += wS[k][c] * bf1(zbuf[k][c][lane]);  // wS broadcast; zbuf 2 lanes/bank (free)
    }
    Zaggb[(size_t)i * DD + k * 64 + lane] = f2bf(acc / l);
}

// ---------------------------------------------------------------------------
// K3: out = relu(H + 0.5 * (Zaggb . Bt2^T) - thr), f32 out. 64x64 MFMA tiling.
// ---------------------------------------------------------------------------
__global__ __launch_bounds__(256) void outgemm_mfma(const u16* __restrict__ Ab, const u16* __restrict__ Btb,
                                                    const float* __restrict__ H, const float* __restrict__ thr,
                                                    float* __restrict__ out) {
    __shared__ short As[64][40];
    __shared__ short Bs[64][40];
    const int t = threadIdx.x;
    const int i0 = blockIdx.x * 64, n0 = blockIdx.y * 64;
    const int w = t >> 6, lane = t & 63;
    const int lm = lane & 15, lg = lane >> 4;
    f32x4 acc[4] = {};
    for (int kc = 0; kc < DD; kc += 32) {
        {   int row = t >> 2, g = t & 3;
            *(short8*)&As[row][g * 8] = *(const short8*)(Ab  + (size_t)(i0 + row) * DD + kc + g * 8);
            *(short8*)&Bs[row][g * 8] = *(const short8*)(Btb + (size_t)(n0 + row) * DD + kc + g * 8);
        }
        __syncthreads();
        short8 af = *(const short8*)&As[w * 16 + lm][lg * 8];
        #pragma unroll
        for (int b = 0; b < 4; b++) {
            short8 bfr = *(const short8*)&Bs[b * 16 + lm][lg * 8];
            acc[b] = __builtin_amdgcn_mfma_f32_16x16x32_bf16(af, bfr, acc[b], 0, 0, 0);
        }
        __syncthreads();
    }
    #pragma unroll
    for (int b = 0; b < 4; b++) {
        const int col = n0 + b * 16 + lm;
        const float th = thr[col];
        #pragma unroll
        for (int q = 0; q < 4; q++) {
            int row = i0 + w * 16 + lg * 4 + q;
            float h = H[(size_t)row * DD + col];
            out[(size_t)row * DD + col] = fmaxf(h + 0.5f * acc[b][q] - th, 0.f);
        }
    }
}

// ---------------------------------------------------------------------------
// K4: orthogonality loss = sum_{k<l} ||U_k^T U_l||_F^2 (f32, atomic reduce).
// ---------------------------------------------------------------------------
__global__ __launch_bounds__(256) void orth_kernel(const float* __restrict__ U, float* __restrict__ loss) {
    int pb = blockIdx.x >> 4;
    int stile = blockIdx.x & 15;
    int idx = pb, k = 0, l = 1;
    for (int kk = 0; kk < 8; kk++) {
        int c = 7 - kk;
        if (idx < c) { k = kk; l = kk + 1 + idx; break; }
        idx -= c;
    }
    int t = threadIdx.x;
    int r = t & 63;
    int s = stile * 4 + (t >> 6);
    const float* Uk = U + (size_t)k * DD * RR;
    const float* Ul = U + (size_t)l * DD * RR;
    float acc = 0.f;
    for (int d = 0; d < DD; d++) {
        acc += Uk[d * RR + r] * Ul[d * RR + s];
    }
    float v = acc * acc;
    #pragma unroll
    for (int off = 32; off; off >>= 1) v += __shfl_down(v, off, 64);
    __shared__ float red[4];
    if ((t & 63) == 0) red[t >> 6] = v;
    __syncthreads();
    if (t == 0) atomicAdd(loss, red[0] + red[1] + red[2] + red[3]);
}

__global__ void loss_fin_kernel(const float* __restrict__ lossf, float* __restrict__ out) {
    out[0] = lossf[0];
}

// ---------------------------------------------------------------------------
extern "C" void kernel_launch(void* const* d_in, const int* in_sizes, int n_in,
                              void* d_out, int out_size, void* d_ws, size_t ws_size,
                              hipStream_t stream) {
    const float* H   = (const float*)d_in[0];
    const float* adj = (const float*)d_in[1];
    const float* U   = (const float*)d_in[2];
    const float* thr = (const float*)d_in[3];
    float* out = (float*)d_out;

    char* ws = (char*)d_ws;
    float* lossA = (float*)ws;                                         // 4 B
    u16*   Hb    = (u16*)(ws + 1024);                                  // 4 MB
    u16*   Zb    = (u16*)(ws + 1024 + 4u  * 1024 * 1024);              // 4 MB
    u16*   Zaggb = (u16*)(ws + 1024 + 8u  * 1024 * 1024);              // 4 MB
    u16*   Bt1   = (u16*)(ws + 1024 + 12u * 1024 * 1024);              // 512 KB
    u16*   Bt2   = (u16*)(ws + 1024 + 12u * 1024 * 1024 + 512u * 1024);// 512 KB

    prep_all<<<2113, 256, 0, stream>>>(H, U, Hb, Bt1, Bt2, lossA);
    zgemm_mfma<<<dim3(64, 8), 256, 0, stream>>>(Hb, Bt1, Zb);
    attn3<<<NN, 512, 0, stream>>>(Zb, adj, Zaggb);
    outgemm_mfma<<<dim3(64, 8), 256, 0, stream>>>(Zaggb, Bt2, H, thr, out);
    orth_kernel<<<28 * 16, 256, 0, stream>>>(U, lossA);
    loss_fin_kernel<<<1, 1, 0, stream>>>(lossA, out + (size_t)NN * DD);
}